// Round 4
// baseline (659.869 us; speedup 1.0000x reference)
//
#include <hip/hip_runtime.h>
#include <math.h>

#define D_ 256
#define NL_ 4
#define NC_ 2
#define L_LEN 1024
#define NSTATE_ 64
#define DIN_ 512
#define H_ 8
#define P_ 64
#define CONVDIM_ 640
#define DPROJ_ 1160
#define EPS_ 1e-5f
#define Q_ 64
#define NCH_ 16   // L_LEN / Q_

__device__ __forceinline__ float siluf(float x) { return x / (1.f + expf(-x)); }
__device__ __forceinline__ float geluf(float x) { return 0.5f * x * (1.f + erff(x * 0.70710678118654752f)); }

// x[b,l,d] = emb[ids[b,l], d] + pos[l, d]
__global__ void k_embed(const int* __restrict__ ids, const float* __restrict__ emb,
                        const float* __restrict__ pos, float* __restrict__ x, int total) {
    int i = blockIdx.x * blockDim.x + threadIdx.x;
    if (i >= total) return;
    int d = i & (D_ - 1);
    int bl = i >> 8;
    int l = bl & (L_LEN - 1);
    x[i] = emb[ids[bl] * D_ + d] + pos[l * D_ + d];
}

// C[M,N] (+)= A[M,K_total] * B[N,K_total]^T over k-range [blockIdx.z*kchunk, +kchunk)
#define AS_(k, r) Asm[(k) * 132 + (r)]
#define BS_(k, r) Bsm[(k) * 68 + (r)]
template <bool ATOMIC>
__global__ void __launch_bounds__(256) gemm_f32t(const float* __restrict__ A,
        const float* __restrict__ B, float* __restrict__ C,
        int M, int N, int K, int kchunk) {
    __shared__ float Asm[16 * 132];
    __shared__ float Bsm[16 * 68];
    const int tid = threadIdx.x;
    const int row0 = blockIdx.y * 128;
    const int col0 = blockIdx.x * 64;
    const int kbase = blockIdx.z * kchunk;
    const int arow = tid >> 2;
    const int akq = tid & 3;
    const int brow = col0 + arow;
    const bool bok = brow < N;

    float4 pa0, pa1, pb0;
    {
        const float* a0 = &A[(size_t)(row0 + arow) * K + kbase + akq * 4];
        pa0 = *(const float4*)a0;
        pa1 = *(const float4*)(a0 + (size_t)64 * K);
        pb0 = bok ? *(const float4*)&B[(size_t)brow * K + kbase + akq * 4]
                  : float4{0.f, 0.f, 0.f, 0.f};
    }
    const int tm = tid >> 4;
    const int tn = tid & 15;
    float acc[8][4] = {};
    const int kend = kbase + kchunk;
    for (int k0 = kbase; k0 < kend; k0 += 16) {
        __syncthreads();
        AS_(akq * 4 + 0, arow) = pa0.x;
        AS_(akq * 4 + 1, arow) = pa0.y;
        AS_(akq * 4 + 2, arow) = pa0.z;
        AS_(akq * 4 + 3, arow) = pa0.w;
        AS_(akq * 4 + 0, arow + 64) = pa1.x;
        AS_(akq * 4 + 1, arow + 64) = pa1.y;
        AS_(akq * 4 + 2, arow + 64) = pa1.z;
        AS_(akq * 4 + 3, arow + 64) = pa1.w;
        BS_(akq * 4 + 0, arow) = pb0.x;
        BS_(akq * 4 + 1, arow) = pb0.y;
        BS_(akq * 4 + 2, arow) = pb0.z;
        BS_(akq * 4 + 3, arow) = pb0.w;
        __syncthreads();
        if (k0 + 16 < kend) {
            const float* a0 = &A[(size_t)(row0 + arow) * K + k0 + 16 + akq * 4];
            pa0 = *(const float4*)a0;
            pa1 = *(const float4*)(a0 + (size_t)64 * K);
            pb0 = bok ? *(const float4*)&B[(size_t)brow * K + k0 + 16 + akq * 4]
                      : float4{0.f, 0.f, 0.f, 0.f};
        }
#pragma unroll
        for (int kk = 0; kk < 16; ++kk) {
            float a[8], b[4];
#pragma unroll
            for (int i = 0; i < 8; ++i) a[i] = AS_(kk, tm * 8 + i);
#pragma unroll
            for (int j = 0; j < 4; ++j) b[j] = BS_(kk, tn * 4 + j);
#pragma unroll
            for (int i = 0; i < 8; ++i)
#pragma unroll
                for (int j = 0; j < 4; ++j) acc[i][j] += a[i] * b[j];
        }
    }
    int cbase = col0 + tn * 4;
#pragma unroll
    for (int i = 0; i < 8; ++i) {
        size_t r = (size_t)(row0 + tm * 8 + i) * N + cbase;
        if (ATOMIC) {
            if (cbase < N) {
#pragma unroll
                for (int j = 0; j < 4; ++j) atomicAdd(&C[r + j], acc[i][j]);
            }
        } else {
            if (cbase + 3 < N) {
                float4 v = {acc[i][0], acc[i][1], acc[i][2], acc[i][3]};
                *(float4*)&C[r] = v;
            } else {
#pragma unroll
                for (int j = 0; j < 4; ++j)
                    if (cbase + j < N) C[r + j] = acc[i][j];
            }
        }
    }
}

// Fused SSM stage A: inline conv+silu + dt + S_local + decay + G + intra-chunk Y + Ctil.
// One block per (chunk c, b, h). zx is the raw in-proj output.
__global__ void __launch_bounds__(256) k_ssmA(const float* __restrict__ zx,
        const float* __restrict__ cw, const float* __restrict__ cb,
        const float* __restrict__ dtbias, const float* __restrict__ Alog,
        const float* __restrict__ Dp,
        float* __restrict__ Sbuf, float* __restrict__ decay,
        float* __restrict__ Ctil, float* __restrict__ y) {
    __shared__ float U[64][65];   // x (silu-conv)
    __shared__ float V[64][65];   // B, later G
    __shared__ float W[64][65];   // C
    __shared__ float sdt[64], cs[64], wj[64];
    const int c = blockIdx.x, bh = blockIdx.y;
    const int b = bh >> 3, h = bh & 7;
    const int l0 = c << 6;
    const int tid = threadIdx.x, wid = tid >> 6, lane = tid & 63;

    // per-thread conv weights/biases (fixed channels)
    const int chx = h * P_ + lane;       // x channel
    const int chb = DIN_ + lane;         // B channel
    const int chc = DIN_ + NSTATE_ + lane;  // C channel
    float wx0 = cw[chx * 4 + 0], wx1 = cw[chx * 4 + 1], wx2 = cw[chx * 4 + 2], wx3 = cw[chx * 4 + 3];
    float wb0 = cw[chb * 4 + 0], wb1 = cw[chb * 4 + 1], wb2 = cw[chb * 4 + 2], wb3 = cw[chb * 4 + 3];
    float wc0 = cw[chc * 4 + 0], wc1 = cw[chc * 4 + 1], wc2 = cw[chc * 4 + 2], wc3 = cw[chc * 4 + 3];
    float bx = cb[chx], bb = cb[chb], bc = cb[chc];

    for (int r = 0; r < 64; r += 4) {
        int j = r + wid;
        int l = l0 + j;
        float ax = bx, ab = bb, ac = bc;
#pragma unroll
        for (int k = 0; k < 4; ++k) {
            int t = l - 3 + k;
            if (t >= 0) {
                const float* row = zx + (size_t)(b * L_LEN + t) * DPROJ_;
                float wxk = (k == 0) ? wx0 : (k == 1) ? wx1 : (k == 2) ? wx2 : wx3;
                float wbk = (k == 0) ? wb0 : (k == 1) ? wb1 : (k == 2) ? wb2 : wb3;
                float wck = (k == 0) ? wc0 : (k == 1) ? wc1 : (k == 2) ? wc2 : wc3;
                ax += wxk * row[DIN_ + chx];
                ab += wbk * row[DIN_ + chb];
                ac += wck * row[DIN_ + chc];
            }
        }
        U[j][lane] = siluf(ax);
        V[j][lane] = siluf(ab);
        W[j][lane] = siluf(ac);
    }
    if (tid < 64) {
        float xv = zx[(size_t)(b * L_LEN + l0 + tid) * DPROJ_ + (DPROJ_ - H_) + h] + dtbias[h];
        float sp = fmaxf(xv, 0.f) + log1pf(expf(-fabsf(xv)));
        sdt[tid] = sp;
        cs[tid] = sp * (-expf(Alog[h]));   // ldA, cumsum'd below
    }
    __syncthreads();
    if (tid == 0) {
        float s = 0.f;
        for (int j = 0; j < 64; ++j) { s += cs[j]; cs[j] = s; }
    }
    __syncthreads();
    if (tid < 64) wj[tid] = expf(cs[63] - cs[tid]) * sdt[tid];
    if (tid == 0) decay[bh * NCH_ + c] = expf(cs[63]);
    __syncthreads();

    // S_local[p][n]
    {
        int p = lane, ng = wid << 4;
        float acc[16] = {};
        for (int j = 0; j < 64; ++j) {
            float wxv = wj[j] * U[j][p];
#pragma unroll
            for (int nn = 0; nn < 16; ++nn) acc[nn] += wxv * V[j][ng + nn];
        }
        float* dst = Sbuf + ((size_t)(bh * NCH_ + c) * P_ + p) * NSTATE_ + ng;
#pragma unroll
        for (int nn = 0; nn < 16; ++nn) dst[nn] = acc[nn];
    }
    // G[i][j] = B_j · C_i  (into registers, then overwrite V)
    int i = lane, jg = wid << 4;
    float g[16] = {};
    for (int n = 0; n < 64; ++n) {
        float cv = W[i][n];
#pragma unroll
        for (int jj = 0; jj < 16; ++jj) g[jj] += cv * V[jg + jj][n];
    }
    __syncthreads();
#pragma unroll
    for (int jj = 0; jj < 16; ++jj) V[i][jg + jj] = g[jj];
    // Ctil[i][n] = e^{cs[i]} * C_i[n]
    {
        float* cd = Ctil + (size_t)(bh * NCH_ + c) * 4096;
        for (int r = 0; r < 64; r += 4) {
            int ii = r + wid;
            cd[ii * 64 + lane] = expf(cs[ii]) * W[ii][lane];
        }
    }
    __syncthreads();
    // intra-chunk Y + D*x
    {
        int pg = jg;
        float acc[16] = {};
        float csi = cs[i];
        for (int j = 0; j < 64; ++j) {
            float w = (j <= i) ? expf(fminf(csi - cs[j], 0.f)) * (sdt[j] * V[i][j]) : 0.f;
#pragma unroll
            for (int pp = 0; pp < 16; ++pp) acc[pp] += w * U[j][pg + pp];
        }
        float Dh = Dp[h];
        float* dst = y + (size_t)(b * L_LEN + l0 + i) * DIN_ + h * P_ + pg;
#pragma unroll
        for (int pp = 0; pp < 16; ++pp) dst[pp] = acc[pp] + Dh * U[i][pg + pp];
    }
}

// In-place cross-chunk scan: Sbuf[c] becomes the INCOMING state for chunk c.
__global__ void k_chunk_scan(float* __restrict__ Sbuf, const float* __restrict__ decay) {
    int bh = blockIdx.x, tid = threadIdx.x;
    float run[16] = {};
    for (int c = 0; c < NCH_; ++c) {
        float* ptr = Sbuf + (size_t)(bh * NCH_ + c) * 4096 + tid * 16;
        float dec = decay[bh * NCH_ + c];
        float tmp[16];
#pragma unroll
        for (int k = 0; k < 16; ++k) tmp[k] = ptr[k];
#pragma unroll
        for (int k = 0; k < 16; ++k) ptr[k] = run[k];
#pragma unroll
        for (int k = 0; k < 16; ++k) run[k] = dec * run[k] + tmp[k];
    }
}

// y[i, h*64+p] += sum_n Ctil[i][n] * S_in[p][n]   (lane = p for coalesced y access)
__global__ void __launch_bounds__(256) k_inter(const float* __restrict__ Sbuf,
        const float* __restrict__ Ctil, float* __restrict__ y) {
    __shared__ float Sm[64][65];
    __shared__ float Cm[64][65];
    const int c = blockIdx.x, bh = blockIdx.y;
    const int b = bh >> 3, h = bh & 7;
    const int l0 = c << 6;
    const int tid = threadIdx.x, wid = tid >> 6, lane = tid & 63;
    const size_t base = (size_t)(bh * NCH_ + c) * 4096;
    for (int r = 0; r < 64; r += 4) {
        int pp = r + wid;
        Sm[pp][lane] = Sbuf[base + pp * 64 + lane];
        Cm[pp][lane] = Ctil[base + pp * 64 + lane];
    }
    __syncthreads();
    int p = lane, ig = wid << 4;
    float acc[16] = {};
    for (int n = 0; n < 64; ++n) {
        float sv = Sm[p][n];
#pragma unroll
        for (int ii = 0; ii < 16; ++ii) acc[ii] += sv * Cm[ig + ii][n];
    }
#pragma unroll
    for (int ii = 0; ii < 16; ++ii) {
        float* dst = y + (size_t)(b * L_LEN + l0 + ig + ii) * DIN_ + h * P_ + p;
        *dst += acc[ii];
    }
}

// y = rmsnorm(y * silu(z)) * norm_w
__global__ void k_gatenorm(const float* __restrict__ zx, const float* __restrict__ nw,
                           float* __restrict__ y) {
    __shared__ float sred[4];
    int bl = blockIdx.x;
    float* yr = y + (size_t)bl * DIN_;
    const float* zr = zx + (size_t)bl * DPROJ_;
    int t = threadIdx.x;
    float g0 = yr[t] * siluf(zr[t]);
    float g1 = yr[t + 256] * siluf(zr[t + 256]);
    float ss = g0 * g0 + g1 * g1;
#pragma unroll
    for (int o = 32; o; o >>= 1) ss += __shfl_xor(ss, o, 64);
    if ((t & 63) == 0) sred[t >> 6] = ss;
    __syncthreads();
    ss = sred[0] + sred[1] + sred[2] + sred[3];
    float scale = rsqrtf(ss * (1.f / DIN_) + EPS_);
    yr[t] = g0 * scale * nw[t];
    yr[t + 256] = g1 * scale * nw[t + 256];
}

// two-stage pooling
__global__ void k_pool1(const float* __restrict__ x, float* __restrict__ psum,
                        float* __restrict__ pmax) {
    int b = blockIdx.y, ch = blockIdx.x, d = threadIdx.x;
    const float* xb = x + ((size_t)(b * L_LEN) + ch * 64) * D_ + d;
    float s = 0.f, m = -INFINITY;
    for (int l = 0; l < 64; ++l) {
        float v = xb[(size_t)l * D_];
        s += v;
        m = fmaxf(m, v);
    }
    psum[(b * 16 + ch) * D_ + d] = s;
    pmax[(b * 16 + ch) * D_ + d] = m;
}

__global__ void k_pool2(const float* __restrict__ psum, const float* __restrict__ pmax,
                        float* __restrict__ pooled) {
    int b = blockIdx.x, d = threadIdx.x;
    float s = 0.f, m = -INFINITY;
    for (int ch = 0; ch < 16; ++ch) {
        s += psum[(b * 16 + ch) * D_ + d];
        m = fmaxf(m, pmax[(b * 16 + ch) * D_ + d]);
    }
    pooled[b * D_ + d] = (s * (1.f / L_LEN) + m) * 0.5f;
}

__global__ void k_head(const float* __restrict__ pooled, const float* __restrict__ pw,
                       const float* __restrict__ pb, const float* __restrict__ c1w,
                       const float* __restrict__ c1b, const float* __restrict__ c2w,
                       const float* __restrict__ c2b, float* __restrict__ out) {
    __shared__ float sp[256], s1[256], s2[128];
    int b = blockIdx.x, t = threadIdx.x;
    sp[t] = pooled[b * D_ + t];
    __syncthreads();
    float acc = pb[t];
    for (int d = 0; d < 256; ++d) acc += sp[d] * pw[t * 256 + d];
    s1[t] = geluf(acc);
    __syncthreads();
    if (t < 128) {
        float a = c1b[t];
        for (int d = 0; d < 256; ++d) a += s1[d] * c1w[t * 256 + d];
        s2[t] = geluf(a);
    }
    __syncthreads();
    if (t < 2) {
        float a = c2b[t];
        for (int d = 0; d < 128; ++d) a += s2[d] * c2w[t * 128 + d];
        out[b * NC_ + t] = a;
    }
}

extern "C" void kernel_launch(void* const* d_in, const int* in_sizes, int n_in,
                              void* d_out, int out_size, void* d_ws, size_t ws_size,
                              hipStream_t stream) {
    const int* ids    = (const int*)d_in[0];
    const float* emb  = (const float*)d_in[1];
    const float* pos  = (const float*)d_in[2];
    const float* Wins = (const float*)d_in[3];
    const float* cw   = (const float*)d_in[4];
    const float* cb   = (const float*)d_in[5];
    const float* dtb  = (const float*)d_in[6];
    const float* Alog = (const float*)d_in[7];
    const float* Dpar = (const float*)d_in[8];
    const float* nw   = (const float*)d_in[9];
    const float* Wout = (const float*)d_in[10];
    const float* pw   = (const float*)d_in[11];
    const float* pb   = (const float*)d_in[12];
    const float* c1w  = (const float*)d_in[13];
    const float* c1b  = (const float*)d_in[14];
    const float* c2w  = (const float*)d_in[15];
    const float* c2b  = (const float*)d_in[16];
    float* out = (float*)d_out;

    float* ws = (float*)d_ws;
    float* x      = ws;                 // 524288
    float* zx     = x + 524288;         // 2375680
    float* y      = zx + 2375680;       // 1048576
    float* Sbuf   = y + 1048576;        // 1048576
    float* Ctil   = Sbuf + 1048576;     // 1048576
    float* decay  = Ctil + 1048576;     // 256
    float* pooled = decay + 256;        // 512
    float* psum   = pooled + 512;       // 8192
    float* pmax   = psum + 8192;        // 8192

    k_embed<<<2048, 256, 0, stream>>>(ids, emb, pos, x, 524288);
    for (int i = 0; i < NL_; ++i) {
        gemm_f32t<false><<<dim3(19, 16, 1), 256, 0, stream>>>(
            x, Wins + (size_t)i * DPROJ_ * D_, zx, 2048, DPROJ_, D_, D_);
        k_ssmA<<<dim3(NCH_, 16), 256, 0, stream>>>(
            zx, cw + (size_t)i * CONVDIM_ * 4, cb + (size_t)i * CONVDIM_,
            dtb + i * H_, Alog + i * H_, Dpar + i * H_, Sbuf, decay, Ctil, y);
        k_chunk_scan<<<16, 256, 0, stream>>>(Sbuf, decay);
        k_inter<<<dim3(NCH_, 16), 256, 0, stream>>>(Sbuf, Ctil, y);
        k_gatenorm<<<2048, 256, 0, stream>>>(zx, nw + (size_t)i * DIN_, y);
        gemm_f32t<true><<<dim3(4, 16, 4), 256, 0, stream>>>(
            y, Wout + (size_t)i * D_ * DIN_, x, 2048, D_, DIN_, 128);
    }
    k_pool1<<<dim3(16, 2), 256, 0, stream>>>(x, psum, pmax);
    k_pool2<<<2, 256, 0, stream>>>(psum, pmax, pooled);
    k_head<<<2, 256, 0, stream>>>(pooled, pw, pb, c1w, c1b, c2w, c2b, out);
}

// Round 5
// 610.560 us; speedup vs baseline: 1.0808x; 1.0808x over previous
//
#include <hip/hip_runtime.h>
#include <math.h>

#define D_ 256
#define NL_ 4
#define NC_ 2
#define L_LEN 1024
#define NSTATE_ 64
#define DIN_ 512
#define H_ 8
#define P_ 64
#define CONVDIM_ 640
#define DPROJ_ 1160
#define EPS_ 1e-5f
#define Q_ 64
#define NCH_ 16   // L_LEN / Q_

__device__ __forceinline__ float siluf(float x) { return x / (1.f + expf(-x)); }
__device__ __forceinline__ float geluf(float x) { return 0.5f * x * (1.f + erff(x * 0.70710678118654752f)); }

// x[b,l,d] = emb[ids[b,l], d] + pos[l, d]
__global__ void k_embed(const int* __restrict__ ids, const float* __restrict__ emb,
                        const float* __restrict__ pos, float* __restrict__ x, int total) {
    int i = blockIdx.x * blockDim.x + threadIdx.x;
    if (i >= total) return;
    int d = i & (D_ - 1);
    int bl = i >> 8;
    int l = bl & (L_LEN - 1);
    x[i] = emb[ids[bl] * D_ + d] + pos[l * D_ + d];
}

// C[M,N] (+)= A[M,K_total] * B[N,K_total]^T over k-range [blockIdx.z*kchunk, +kchunk)
#define AS_(k, r) Asm[(k) * 132 + (r)]
#define BS_(k, r) Bsm[(k) * 68 + (r)]
template <bool ATOMIC>
__global__ void __launch_bounds__(256) gemm_f32t(const float* __restrict__ A,
        const float* __restrict__ B, float* __restrict__ C,
        int M, int N, int K, int kchunk) {
    __shared__ float Asm[16 * 132];
    __shared__ float Bsm[16 * 68];
    const int tid = threadIdx.x;
    const int row0 = blockIdx.y * 128;
    const int col0 = blockIdx.x * 64;
    const int kbase = blockIdx.z * kchunk;
    const int arow = tid >> 2;
    const int akq = tid & 3;
    const int brow = col0 + arow;
    const bool bok = brow < N;

    float4 pa0, pa1, pb0;
    {
        const float* a0 = &A[(size_t)(row0 + arow) * K + kbase + akq * 4];
        pa0 = *(const float4*)a0;
        pa1 = *(const float4*)(a0 + (size_t)64 * K);
        pb0 = bok ? *(const float4*)&B[(size_t)brow * K + kbase + akq * 4]
                  : float4{0.f, 0.f, 0.f, 0.f};
    }
    const int tm = tid >> 4;
    const int tn = tid & 15;
    float acc[8][4] = {};
    const int kend = kbase + kchunk;
    for (int k0 = kbase; k0 < kend; k0 += 16) {
        __syncthreads();
        AS_(akq * 4 + 0, arow) = pa0.x;
        AS_(akq * 4 + 1, arow) = pa0.y;
        AS_(akq * 4 + 2, arow) = pa0.z;
        AS_(akq * 4 + 3, arow) = pa0.w;
        AS_(akq * 4 + 0, arow + 64) = pa1.x;
        AS_(akq * 4 + 1, arow + 64) = pa1.y;
        AS_(akq * 4 + 2, arow + 64) = pa1.z;
        AS_(akq * 4 + 3, arow + 64) = pa1.w;
        BS_(akq * 4 + 0, arow) = pb0.x;
        BS_(akq * 4 + 1, arow) = pb0.y;
        BS_(akq * 4 + 2, arow) = pb0.z;
        BS_(akq * 4 + 3, arow) = pb0.w;
        __syncthreads();
        if (k0 + 16 < kend) {
            const float* a0 = &A[(size_t)(row0 + arow) * K + k0 + 16 + akq * 4];
            pa0 = *(const float4*)a0;
            pa1 = *(const float4*)(a0 + (size_t)64 * K);
            pb0 = bok ? *(const float4*)&B[(size_t)brow * K + k0 + 16 + akq * 4]
                      : float4{0.f, 0.f, 0.f, 0.f};
        }
#pragma unroll
        for (int kk = 0; kk < 16; ++kk) {
            float a[8], b[4];
#pragma unroll
            for (int i = 0; i < 8; ++i) a[i] = AS_(kk, tm * 8 + i);
#pragma unroll
            for (int j = 0; j < 4; ++j) b[j] = BS_(kk, tn * 4 + j);
#pragma unroll
            for (int i = 0; i < 8; ++i)
#pragma unroll
                for (int j = 0; j < 4; ++j) acc[i][j] += a[i] * b[j];
        }
    }
    int cbase = col0 + tn * 4;
#pragma unroll
    for (int i = 0; i < 8; ++i) {
        size_t r = (size_t)(row0 + tm * 8 + i) * N + cbase;
        if (ATOMIC) {
            if (cbase < N) {
#pragma unroll
                for (int j = 0; j < 4; ++j) atomicAdd(&C[r + j], acc[i][j]);
            }
        } else {
            if (cbase + 3 < N) {
                float4 v = {acc[i][0], acc[i][1], acc[i][2], acc[i][3]};
                *(float4*)&C[r] = v;
            } else {
#pragma unroll
                for (int j = 0; j < 4; ++j)
                    if (cbase + j < N) C[r + j] = acc[i][j];
            }
        }
    }
}

// Fused SSM: conv+silu + dt + S_local + decay + Ctil + G(masked, transposed) + intra Y.
// One block per (chunk c, b, h). Register-tiled 4x4 microkernels; all LDS reads b128.
__global__ void __launch_bounds__(256) k_ssmA(const float* __restrict__ zx,
        const float* __restrict__ cw, const float* __restrict__ cb,
        const float* __restrict__ dtbias, const float* __restrict__ Alog,
        const float* __restrict__ Dp,
        float* __restrict__ Sbuf, float* __restrict__ decay,
        float* __restrict__ Ctil, float* __restrict__ y) {
    __shared__ float U[64][65];   // X[j][p] (silu-conv x)
    __shared__ float V[64][65];   // B[j][n]; after G-phase: Wt[j][i]
    __shared__ float W[64][65];   // C[i][n]
    __shared__ float sdt[64], cs[64], wj[64];
    const int c = blockIdx.x, bh = blockIdx.y;
    const int b = bh >> 3, h = bh & 7;
    const int l0 = c << 6;
    const int tid = threadIdx.x, wid = tid >> 6, lane = tid & 63;

    // ---- conv + silu into LDS ----
    const int chx = h * P_ + lane;
    const int chb = DIN_ + lane;
    const int chc = DIN_ + NSTATE_ + lane;
    float wx0 = cw[chx * 4 + 0], wx1 = cw[chx * 4 + 1], wx2 = cw[chx * 4 + 2], wx3 = cw[chx * 4 + 3];
    float wb0 = cw[chb * 4 + 0], wb1 = cw[chb * 4 + 1], wb2 = cw[chb * 4 + 2], wb3 = cw[chb * 4 + 3];
    float wc0 = cw[chc * 4 + 0], wc1 = cw[chc * 4 + 1], wc2 = cw[chc * 4 + 2], wc3 = cw[chc * 4 + 3];
    float bx = cb[chx], bb = cb[chb], bc = cb[chc];

    for (int r = 0; r < 64; r += 4) {
        int j = r + wid;
        int l = l0 + j;
        float ax = bx, ab = bb, ac = bc;
#pragma unroll
        for (int k = 0; k < 4; ++k) {
            int t = l - 3 + k;
            if (t >= 0) {
                const float* row = zx + (size_t)(b * L_LEN + t) * DPROJ_;
                float wxk = (k == 0) ? wx0 : (k == 1) ? wx1 : (k == 2) ? wx2 : wx3;
                float wbk = (k == 0) ? wb0 : (k == 1) ? wb1 : (k == 2) ? wb2 : wb3;
                float wck = (k == 0) ? wc0 : (k == 1) ? wc1 : (k == 2) ? wc2 : wc3;
                ax += wxk * row[DIN_ + chx];
                ab += wbk * row[DIN_ + chb];
                ac += wck * row[DIN_ + chc];
            }
        }
        U[j][lane] = siluf(ax);
        V[j][lane] = siluf(ab);
        W[j][lane] = siluf(ac);
    }
    if (tid < 64) {
        float xv = zx[(size_t)(b * L_LEN + l0 + tid) * DPROJ_ + (DPROJ_ - H_) + h] + dtbias[h];
        float sp = fmaxf(xv, 0.f) + log1pf(expf(-fabsf(xv)));
        sdt[tid] = sp;
        cs[tid] = sp * (-expf(Alog[h]));
    }
    __syncthreads();
    if (tid == 0) {
        float s = 0.f;
        for (int j = 0; j < 64; ++j) { s += cs[j]; cs[j] = s; }
    }
    __syncthreads();
    if (tid < 64) wj[tid] = expf(cs[63] - cs[tid]) * sdt[tid];
    if (tid == 0) decay[bh * NCH_ + c] = expf(cs[63]);
    __syncthreads();

    const int t4 = (tid & 15) * 4;   // col group
    const int r4 = (tid >> 4) * 4;   // row group
    const size_t sbase = (size_t)(bh * NCH_ + c) * 4096;

    // ---- S_local[p][n] = sum_j wj[j]*X[j][p]*B[j][n] ; rows p=r4.., cols n=t4.. ----
    {
        float acc[4][4] = {};
        for (int j = 0; j < 64; ++j) {
            float w = wj[j];
            float4 xv = *(const float4*)&U[j][r4];
            float4 bv = *(const float4*)&V[j][t4];
            float xw[4] = {xv.x * w, xv.y * w, xv.z * w, xv.w * w};
            float bs[4] = {bv.x, bv.y, bv.z, bv.w};
#pragma unroll
            for (int ii = 0; ii < 4; ++ii)
#pragma unroll
                for (int nn = 0; nn < 4; ++nn) acc[ii][nn] += xw[ii] * bs[nn];
        }
#pragma unroll
        for (int ii = 0; ii < 4; ++ii) {
            float4 v = {acc[ii][0], acc[ii][1], acc[ii][2], acc[ii][3]};
            *(float4*)&Sbuf[sbase + (size_t)(r4 + ii) * 64 + t4] = v;
        }
    }
    // ---- Ctil[i][n] = e^{cs[i]} * C[i][n] ----
    for (int r = 0; r < 64; r += 4) {
        int ii = r + wid;
        Ctil[sbase + ii * 64 + lane] = expf(cs[ii]) * W[ii][lane];
    }
    // ---- G[i][j] = sum_n C[i][n]*B[j][n]; i=r4.., j=t4.. (NT, 4x4) ----
    float g[4][4] = {};
    for (int ng = 0; ng < 64; ng += 4) {
        float4 cf[4], bf[4];
#pragma unroll
        for (int ii = 0; ii < 4; ++ii) cf[ii] = *(const float4*)&W[r4 + ii][ng];
#pragma unroll
        for (int jj = 0; jj < 4; ++jj) bf[jj] = *(const float4*)&V[t4 + jj][ng];
#pragma unroll
        for (int ii = 0; ii < 4; ++ii)
#pragma unroll
            for (int jj = 0; jj < 4; ++jj)
                g[ii][jj] += cf[ii].x * bf[jj].x + cf[ii].y * bf[jj].y +
                             cf[ii].z * bf[jj].z + cf[ii].w * bf[jj].w;
    }
    // masked decay weight, transposed: Wt[j][i]
    float wt[4][4];
#pragma unroll
    for (int ii = 0; ii < 4; ++ii) {
        int i = r4 + ii;
        float csi = cs[i];
#pragma unroll
        for (int jj = 0; jj < 4; ++jj) {
            int j = t4 + jj;
            wt[ii][jj] = (j <= i) ? expf(fminf(csi - cs[j], 0.f)) * sdt[j] * g[ii][jj] : 0.f;
        }
    }
    __syncthreads();   // everyone done reading V (B)
#pragma unroll
    for (int jj = 0; jj < 4; ++jj) {
        float4 v = {wt[0][jj], wt[1][jj], wt[2][jj], wt[3][jj]};
        *(float4*)&V[t4 + jj][r4] = v;
    }
    __syncthreads();
    // ---- intra Y[i][p] = sum_j Wt[j][i]*X[j][p]  + Dh*X[i][p]; i=r4.., p=t4.. ----
    {
        float acc[4][4] = {};
        for (int j = 0; j < 64; ++j) {
            float4 wv = *(const float4*)&V[j][r4];
            float4 xv = *(const float4*)&U[j][t4];
            float ws[4] = {wv.x, wv.y, wv.z, wv.w};
            float xs[4] = {xv.x, xv.y, xv.z, xv.w};
#pragma unroll
            for (int ii = 0; ii < 4; ++ii)
#pragma unroll
                for (int pp = 0; pp < 4; ++pp) acc[ii][pp] += ws[ii] * xs[pp];
        }
        float Dh = Dp[h];
#pragma unroll
        for (int ii = 0; ii < 4; ++ii) {
            float4 xv = *(const float4*)&U[r4 + ii][t4];
            float4 v = {acc[ii][0] + Dh * xv.x, acc[ii][1] + Dh * xv.y,
                        acc[ii][2] + Dh * xv.z, acc[ii][3] + Dh * xv.w};
            *(float4*)&y[(size_t)(b * L_LEN + l0 + r4 + ii) * DIN_ + h * P_ + t4] = v;
        }
    }
}

// In-place cross-chunk scan: Sbuf[c] becomes the INCOMING state for chunk c.
__global__ void k_chunk_scan(float* __restrict__ Sbuf, const float* __restrict__ decay) {
    int bh = blockIdx.x, tid = threadIdx.x;
    float run[16] = {};
    for (int c = 0; c < NCH_; ++c) {
        float* ptr = Sbuf + (size_t)(bh * NCH_ + c) * 4096 + tid * 16;
        float dec = decay[bh * NCH_ + c];
        float tmp[16];
#pragma unroll
        for (int k = 0; k < 16; ++k) tmp[k] = ptr[k];
#pragma unroll
        for (int k = 0; k < 16; ++k) ptr[k] = run[k];
#pragma unroll
        for (int k = 0; k < 16; ++k) run[k] = dec * run[k] + tmp[k];
    }
}

// y[i, h*64+p] += sum_n Ctil[i][n] * S_in[p][n]  (register-tiled NT 4x4)
__global__ void __launch_bounds__(256) k_inter(const float* __restrict__ Sbuf,
        const float* __restrict__ Ctil, float* __restrict__ y) {
    __shared__ float Sm[64][65];
    __shared__ float Cm[64][65];
    const int c = blockIdx.x, bh = blockIdx.y;
    const int b = bh >> 3, h = bh & 7;
    const int l0 = c << 6;
    const int tid = threadIdx.x, wid = tid >> 6, lane = tid & 63;
    const size_t base = (size_t)(bh * NCH_ + c) * 4096;
    for (int r = 0; r < 64; r += 4) {
        int pp = r + wid;
        Sm[pp][lane] = Sbuf[base + pp * 64 + lane];
        Cm[pp][lane] = Ctil[base + pp * 64 + lane];
    }
    __syncthreads();
    const int t4 = (tid & 15) * 4;   // p group
    const int r4 = (tid >> 4) * 4;   // i group
    float acc[4][4] = {};
    for (int ng = 0; ng < 64; ng += 4) {
        float4 cf[4], sf[4];
#pragma unroll
        for (int ii = 0; ii < 4; ++ii) cf[ii] = *(const float4*)&Cm[r4 + ii][ng];
#pragma unroll
        for (int pp = 0; pp < 4; ++pp) sf[pp] = *(const float4*)&Sm[t4 + pp][ng];
#pragma unroll
        for (int ii = 0; ii < 4; ++ii)
#pragma unroll
            for (int pp = 0; pp < 4; ++pp)
                acc[ii][pp] += cf[ii].x * sf[pp].x + cf[ii].y * sf[pp].y +
                               cf[ii].z * sf[pp].z + cf[ii].w * sf[pp].w;
    }
#pragma unroll
    for (int ii = 0; ii < 4; ++ii) {
        float* dst = &y[(size_t)(b * L_LEN + l0 + r4 + ii) * DIN_ + h * P_ + t4];
        float4 v = *(const float4*)dst;
        v.x += acc[ii][0]; v.y += acc[ii][1]; v.z += acc[ii][2]; v.w += acc[ii][3];
        *(float4*)dst = v;
    }
}

// y = rmsnorm(y * silu(z)) * norm_w
__global__ void k_gatenorm(const float* __restrict__ zx, const float* __restrict__ nw,
                           float* __restrict__ y) {
    __shared__ float sred[4];
    int bl = blockIdx.x;
    float* yr = y + (size_t)bl * DIN_;
    const float* zr = zx + (size_t)bl * DPROJ_;
    int t = threadIdx.x;
    float g0 = yr[t] * siluf(zr[t]);
    float g1 = yr[t + 256] * siluf(zr[t + 256]);
    float ss = g0 * g0 + g1 * g1;
#pragma unroll
    for (int o = 32; o; o >>= 1) ss += __shfl_xor(ss, o, 64);
    if ((t & 63) == 0) sred[t >> 6] = ss;
    __syncthreads();
    ss = sred[0] + sred[1] + sred[2] + sred[3];
    float scale = rsqrtf(ss * (1.f / DIN_) + EPS_);
    yr[t] = g0 * scale * nw[t];
    yr[t + 256] = g1 * scale * nw[t + 256];
}

// two-stage pooling
__global__ void k_pool1(const float* __restrict__ x, float* __restrict__ psum,
                        float* __restrict__ pmax) {
    int b = blockIdx.y, ch = blockIdx.x, d = threadIdx.x;
    const float* xb = x + ((size_t)(b * L_LEN) + ch * 64) * D_ + d;
    float s = 0.f, m = -INFINITY;
    for (int l = 0; l < 64; ++l) {
        float v = xb[(size_t)l * D_];
        s += v;
        m = fmaxf(m, v);
    }
    psum[(b * 16 + ch) * D_ + d] = s;
    pmax[(b * 16 + ch) * D_ + d] = m;
}

__global__ void k_pool2(const float* __restrict__ psum, const float* __restrict__ pmax,
                        float* __restrict__ pooled) {
    int b = blockIdx.x, d = threadIdx.x;
    float s = 0.f, m = -INFINITY;
    for (int ch = 0; ch < 16; ++ch) {
        s += psum[(b * 16 + ch) * D_ + d];
        m = fmaxf(m, pmax[(b * 16 + ch) * D_ + d]);
    }
    pooled[b * D_ + d] = (s * (1.f / L_LEN) + m) * 0.5f;
}

__global__ void k_head(const float* __restrict__ pooled, const float* __restrict__ pw,
                       const float* __restrict__ pb, const float* __restrict__ c1w,
                       const float* __restrict__ c1b, const float* __restrict__ c2w,
                       const float* __restrict__ c2b, float* __restrict__ out) {
    __shared__ float sp[256], s1[256], s2[128];
    int b = blockIdx.x, t = threadIdx.x;
    sp[t] = pooled[b * D_ + t];
    __syncthreads();
    float acc = pb[t];
    for (int d = 0; d < 256; ++d) acc += sp[d] * pw[t * 256 + d];
    s1[t] = geluf(acc);
    __syncthreads();
    if (t < 128) {
        float a = c1b[t];
        for (int d = 0; d < 256; ++d) a += s1[d] * c1w[t * 256 + d];
        s2[t] = geluf(a);
    }
    __syncthreads();
    if (t < 2) {
        float a = c2b[t];
        for (int d = 0; d < 128; ++d) a += s2[d] * c2w[t * 128 + d];
        out[b * NC_ + t] = a;
    }
}

extern "C" void kernel_launch(void* const* d_in, const int* in_sizes, int n_in,
                              void* d_out, int out_size, void* d_ws, size_t ws_size,
                              hipStream_t stream) {
    const int* ids    = (const int*)d_in[0];
    const float* emb  = (const float*)d_in[1];
    const float* pos  = (const float*)d_in[2];
    const float* Wins = (const float*)d_in[3];
    const float* cw   = (const float*)d_in[4];
    const float* cb   = (const float*)d_in[5];
    const float* dtb  = (const float*)d_in[6];
    const float* Alog = (const float*)d_in[7];
    const float* Dpar = (const float*)d_in[8];
    const float* nw   = (const float*)d_in[9];
    const float* Wout = (const float*)d_in[10];
    const float* pw   = (const float*)d_in[11];
    const float* pb   = (const float*)d_in[12];
    const float* c1w  = (const float*)d_in[13];
    const float* c1b  = (const float*)d_in[14];
    const float* c2w  = (const float*)d_in[15];
    const float* c2b  = (const float*)d_in[16];
    float* out = (float*)d_out;

    float* ws = (float*)d_ws;
    float* x      = ws;                 // 524288
    float* zx     = x + 524288;         // 2375680
    float* y      = zx + 2375680;       // 1048576
    float* Sbuf   = y + 1048576;        // 1048576
    float* Ctil   = Sbuf + 1048576;     // 1048576
    float* decay  = Ctil + 1048576;     // 256
    float* pooled = decay + 256;        // 512
    float* psum   = pooled + 512;       // 8192
    float* pmax   = psum + 8192;        // 8192

    k_embed<<<2048, 256, 0, stream>>>(ids, emb, pos, x, 524288);
    for (int i = 0; i < NL_; ++i) {
        gemm_f32t<false><<<dim3(19, 16, 1), 256, 0, stream>>>(
            x, Wins + (size_t)i * DPROJ_ * D_, zx, 2048, DPROJ_, D_, D_);
        k_ssmA<<<dim3(NCH_, 16), 256, 0, stream>>>(
            zx, cw + (size_t)i * CONVDIM_ * 4, cb + (size_t)i * CONVDIM_,
            dtb + i * H_, Alog + i * H_, Dpar + i * H_, Sbuf, decay, Ctil, y);
        k_chunk_scan<<<16, 256, 0, stream>>>(Sbuf, decay);
        k_inter<<<dim3(NCH_, 16), 256, 0, stream>>>(Sbuf, Ctil, y);
        k_gatenorm<<<2048, 256, 0, stream>>>(zx, nw + (size_t)i * DIN_, y);
        gemm_f32t<true><<<dim3(4, 16, 4), 256, 0, stream>>>(
            y, Wout + (size_t)i * D_ * DIN_, x, 2048, D_, DIN_, 128);
    }
    k_pool1<<<dim3(16, 2), 256, 0, stream>>>(x, psum, pmax);
    k_pool2<<<2, 256, 0, stream>>>(psum, pmax, pooled);
    k_head<<<2, 256, 0, stream>>>(pooled, pw, pb, c1w, c1b, c2w, c2b, out);
}